// Round 3
// baseline (27.132 us; speedup 1.0000x reference)
//
#include <hip/hip_runtime.h>

// out[b,e,t] = sum_{s<=t} x[s]*(w0[s]*dv0^(t-s) + w1[t]*dv1^(t-s)) + bias[t]
//   P[t] = dv0*P[t-1] + x[t]*w0[t];  Q[t] = dv1*Q[t-1] + x[t]
//   out[t] = P[t] + w1[t]*Q[t] + bias[t]
// One row (S=2048) per 256-thread block, 8 contiguous elems/thread, all in
// registers (no LDS staging). Two-pass scan: pass1 segment carries ->
// wave shfl-scan -> cross-wave combine (one barrier) -> pass2 recompute
// seeded with carry, fused with w1/bias and direct global stores.

#define S_LEN 2048
#define THREADS 256

__global__ __launch_bounds__(THREADS, 8)
void crcl_kernel(const float* __restrict__ x,
                 const float* __restrict__ weight,
                 const float* __restrict__ bias,
                 const float* __restrict__ decay,
                 float* __restrict__ out)
{
    __shared__ float carry[2][4];   // per-wave segment totals [p/q][wave]

    const int t    = (int)threadIdx.x;
    const int lane = t & 63;
    const int w    = t >> 6;
    const long row = (long)blockIdx.x;

    // ---- issue all global loads up front (compiler overlaps latency) ----
    const float4* x4  = (const float4*)(x + row * (long)S_LEN);
    const float4* w04 = (const float4*)weight;           // weight[0][:]
    const float4* w14 = (const float4*)(weight + S_LEN); // weight[1][:]
    const float4* b4  = (const float4*)bias;

    const float4 xa = x4[2 * t],  xb = x4[2 * t + 1];
    const float4 wa = w04[2 * t], wb = w04[2 * t + 1];
    const float4 va = w14[2 * t], vb = w14[2 * t + 1];
    const float4 ba = b4[2 * t],  bb = b4[2 * t + 1];

    const float dv0 = fminf(fmaxf(decay[0], 0.9f), 1.0f);
    const float dv1 = fminf(fmaxf(decay[1], 0.9f), 1.0f);

    const float xs[8] = {xa.x, xa.y, xa.z, xa.w, xb.x, xb.y, xb.z, xb.w};
    const float ws[8] = {wa.x, wa.y, wa.z, wa.w, wb.x, wb.y, wb.z, wb.w};

    // ---- pass 1: per-thread segment totals only ----
    float pc = 0.0f, qc = 0.0f;
#pragma unroll
    for (int k = 0; k < 8; ++k) {
        pc = fmaf(dv0, pc, xs[k] * ws[k]);
        qc = fmaf(dv1, qc, xs[k]);
    }

    // ---- wave Kogge-Stone scan of segment carries (A = dv^8) ----
    float A8_0 = dv0 * dv0; A8_0 *= A8_0; A8_0 *= A8_0;   // dv0^8
    float A8_1 = dv1 * dv1; A8_1 *= A8_1; A8_1 *= A8_1;   // dv1^8

    float cp = pc, cq = qc;
    float k0 = A8_0, k1 = A8_1;
#pragma unroll
    for (int d = 1; d < 64; d <<= 1) {
        const float up = __shfl_up(cp, (unsigned)d, 64);
        const float uq = __shfl_up(cq, (unsigned)d, 64);
        if (lane >= d) {
            cp = fmaf(k0, up, cp);
            cq = fmaf(k1, uq, cq);
        }
        k0 *= k0;
        k1 *= k1;
    }
    float cin_p = __shfl_up(cp, 1u, 64);
    float cin_q = __shfl_up(cq, 1u, 64);
    if (lane == 0) { cin_p = 0.0f; cin_q = 0.0f; }

    // ---- cross-wave carry combine (one barrier) ----
    if (lane == 63) { carry[0][w] = cp; carry[1][w] = cq; }
    __syncthreads();

    float A512_0 = A8_0, A512_1 = A8_1;                   // dv^512 via 6 squarings
#pragma unroll
    for (int b = 0; b < 6; ++b) { A512_0 *= A512_0; A512_1 *= A512_1; }

    float cwp = 0.0f, cwq = 0.0f;                         // carry into this wave
#pragma unroll
    for (int v = 0; v < 3; ++v) {
        if (v < w) {
            cwp = fmaf(cwp, A512_0, carry[0][v]);
            cwq = fmaf(cwq, A512_1, carry[1][v]);
        }
    }
    // fold wave carry into lane carry: + cw * dv^(8*lane)
    const float e8 = (float)(8 * lane);
    const float pwl_0 = exp2f(e8 * log2f(dv0));
    const float pwl_1 = exp2f(e8 * log2f(dv1));
    cin_p = fmaf(cwp, pwl_0, cin_p);
    cin_q = fmaf(cwq, pwl_1, cin_q);

    // ---- pass 2: recompute scan seeded with carry, fused epilogue ----
    const float vs[8] = {va.x, va.y, va.z, va.w, vb.x, vb.y, vb.z, vb.w};
    const float bs[8] = {ba.x, ba.y, ba.z, ba.w, bb.x, bb.y, bb.z, bb.w};

    float p2 = cin_p, q2 = cin_q;
    float ys[8];
#pragma unroll
    for (int k = 0; k < 8; ++k) {
        p2 = fmaf(dv0, p2, xs[k] * ws[k]);
        q2 = fmaf(dv1, q2, xs[k]);
        ys[k] = fmaf(vs[k], q2, p2) + bs[k];
    }

    float4* o4 = (float4*)(out + row * (long)S_LEN);
    o4[2 * t]     = make_float4(ys[0], ys[1], ys[2], ys[3]);
    o4[2 * t + 1] = make_float4(ys[4], ys[5], ys[6], ys[7]);
}

extern "C" void kernel_launch(void* const* d_in, const int* in_sizes, int n_in,
                              void* d_out, int out_size, void* d_ws, size_t ws_size,
                              hipStream_t stream) {
    const float* x      = (const float*)d_in[0];
    const float* weight = (const float*)d_in[1];
    const float* bias   = (const float*)d_in[2];
    const float* decay  = (const float*)d_in[3];
    float* out = (float*)d_out;

    const int nrows = in_sizes[0] / S_LEN;   // B*E = 8192 rows, one block each
    hipLaunchKernelGGL(crcl_kernel, dim3(nrows), dim3(THREADS), 0, stream,
                       x, weight, bias, decay, out);
}